// Round 3
// baseline (205.547 us; speedup 1.0000x reference)
//
#include <hip/hip_runtime.h>
#include <math.h>

#define N_NODES 20000
#define N_EDGES 160000
#define EPSB 1e-5f
#define SLOPE 0.01f

// ---- workspace layout (float element offsets) ----
#define OFF_DEG    0        // int[20000]
#define OFF_DINV   20000    // float[20000]
#define OFF_AGG1   40000    // float[20000]
#define OFF_AGG2   60000    // float[20000]
#define OFF_CNODE  80000    // float[20000]
#define OFF_V      100000   // float[1024]
#define OFF_U      101024   // float[1024]
#define OFF_R      102048   // float[256]
#define OFF_RU     102304   // float[256]
#define OFF_S      102560   // float[256]
#define OFF_ZEND   102816   // end of zeroed region
#define OFF_WPAD   102816   // float[256*128]  (lW2 padded 124->128 cols)
#define OFF_LB2P   135584   // float[128]
#define OFF_RRS    135712   // float4[256]  (16B aligned)

// K1: blocks [0,256) compute v,u (c split 64 ways for occupancy); blocks [256,881) do degree atomics.
__global__ void K1_deg_v(const int* __restrict__ dst, int* __restrict__ deg,
                         const float* __restrict__ W1, const float* __restrict__ b1,
                         const float* __restrict__ W2,
                         float* __restrict__ v, float* __restrict__ u) {
    int b = blockIdx.x;
    if (b < 256) {
        int k  = (b & 3) * 256 + threadIdx.x;   // 0..1023
        int c0 = (b >> 2) * 32;                 // 64 chunks of 32
        float av = 0.f, au = 0.f;
        for (int c = c0; c < c0 + 32; ++c) {
            float w = W2[c * 1024 + k];         // coalesced across threads
            av = fmaf(W1[c], w, av);
            au = fmaf(b1[c], w, au);
        }
        atomicAdd(&v[k], av);
        atomicAdd(&u[k], au);
    } else {
        int e = (b - 256) * 256 + threadIdx.x;
        if (e < N_EDGES) atomicAdd(&deg[dst[e]], 1);
    }
}

// K2: dinv + self-loop init for agg1 and cnode
__global__ void K2_prep(const int* __restrict__ deg, const float* __restrict__ x,
                        float* __restrict__ dinv, float* __restrict__ agg1,
                        float* __restrict__ cnode) {
    int i = blockIdx.x * blockDim.x + threadIdx.x;
    if (i < N_NODES) {
        float di = rsqrtf((float)(deg[i] + 1));  // +1 = self loop
        dinv[i] = di;
        float d2 = di * di;
        agg1[i]  = d2 * x[i];
        cnode[i] = d2;
    }
}

// K3: first edge aggregation (agg1, cnode)
__global__ void K3_edges1(const int* __restrict__ src, const int* __restrict__ dst,
                          const float* __restrict__ dinv, const float* __restrict__ x,
                          float* __restrict__ agg1, float* __restrict__ cnode) {
    int e = blockIdx.x * blockDim.x + threadIdx.x;
    if (e < N_EDGES) {
        int s = src[e], d = dst[e];
        float nrm = dinv[s] * dinv[d];
        atomicAdd(&agg1[d], nrm * x[s]);
        atomicAdd(&cnode[d], nrm);
    }
}

// K4: blocks [0,79) agg2 self-loop init; blocks [79,111) fold BN + Linear1 into r/ru/s.
__global__ void K4_init_rs(const float* __restrict__ dinv, const float* __restrict__ agg1,
                           float* __restrict__ agg2,
                           const float* __restrict__ v, const float* __restrict__ u,
                           const float* __restrict__ gamma, const float* __restrict__ beta,
                           const float* __restrict__ mean, const float* __restrict__ var,
                           const float* __restrict__ b2, const float* __restrict__ lW1,
                           const float* __restrict__ lb1,
                           float* __restrict__ r, float* __restrict__ ru, float* __restrict__ s) {
    int b = blockIdx.x;
    if (b < 79) {
        int i = b * 256 + threadIdx.x;
        if (i < N_NODES) agg2[i] = dinv[i] * dinv[i] * agg1[i];
    } else {
        int m  = threadIdx.x;               // 0..255
        int k0 = (b - 79) * 32;             // 32 chunks of 32
        float ar = 0.f, aru = 0.f, as = 0.f;
        for (int k = k0; k < k0 + 32; ++k) {
            float g = gamma[k] * rsqrtf(var[k] + EPSB);
            float w = lW1[k * 256 + m];
            ar  = fmaf(v[k] * g, w, ar);
            aru = fmaf(u[k] * g, w, aru);
            as  = fmaf(fmaf(b2[k] - mean[k], g, beta[k]), w, as);
        }
        if (b == 79) as += lb1[m];
        atomicAdd(&r[m], ar);
        atomicAdd(&ru[m], aru);
        atomicAdd(&s[m], as);
    }
}

// K5: blocks [0,625) second edge aggregation (agg2); blocks [625,753) pad lW2 + pack rrs.
__global__ void K5_edges2_pad(const int* __restrict__ src, const int* __restrict__ dst,
                              const float* __restrict__ dinv, const float* __restrict__ agg1,
                              float* __restrict__ agg2,
                              const float* __restrict__ lW2, const float* __restrict__ lb2,
                              const float* __restrict__ r, const float* __restrict__ ru,
                              const float* __restrict__ s,
                              float* __restrict__ wpad, float* __restrict__ lb2p,
                              float4* __restrict__ rrs) {
    int b = blockIdx.x;
    if (b < 625) {
        int e = b * 256 + threadIdx.x;
        if (e < N_EDGES) {
            int sn = src[e], d = dst[e];
            atomicAdd(&agg2[d], dinv[sn] * dinv[d] * agg1[sn]);
        }
    } else {
        int i = (b - 625) * 256 + threadIdx.x;
        if (i < 256 * 128) {
            int m = i >> 7, j = i & 127;
            wpad[i] = (j < 124) ? lW2[m * 124 + j] : 0.f;
        }
        if (i < 128) lb2p[i] = (i < 124) ? lb2[i] : -1e30f;
        if (i < 256) rrs[i] = make_float4(r[i], ru[i], s[i], 0.f);
    }
}

// K6 final stage: per node  t[m] = leaky(agg2*r[m] + cnode*ru[m] + s[m]);
// logits = t @ lW2 + lb2; out = log_softmax(logits).
// 1024 thr = 16 waves/block; block covers 64 nodes (node = lane); wave w owns
// 8-col chunk [8w, 8w+8) -> acc[8] in VGPRs, 5008 waves total (round-2's 1252
// waves @ Occupancy=12% was the limiter). Weight addresses wave-uniform ->
// broadcast L2 loads. LDS row stride 133 (odd) -> 2-way bank alias only (free).
#define RSTRIDE 133
__global__ __launch_bounds__(1024) void K6_final(
    const float* __restrict__ agg2, const float* __restrict__ cnode,
    const float4* __restrict__ rrs, const float4* __restrict__ wpad4,
    const float* __restrict__ lb2p, float* __restrict__ out) {
    __shared__ float red[64 * RSTRIDE];   // 34 KB
    int tid  = threadIdx.x;
    int lane = tid & 63;
    int wave = __builtin_amdgcn_readfirstlane(tid >> 6);  // 0..15, provably uniform
    int node = blockIdx.x * 64 + lane;
    bool valid = node < N_NODES;
    float a  = valid ? agg2[node]  : 0.f;
    float cn = valid ? cnode[node] : 0.f;

    float acc[8];
#pragma unroll
    for (int j = 0; j < 8; ++j) acc[j] = 0.f;

    const int jq4 = wave * 2;   // float4 offset of this wave's 8-col chunk
#pragma unroll 8
    for (int m = 0; m < 256; ++m) {
        float4 c = rrs[m];                                  // uniform -> s_load
        float t = fmaf(cn, c.y, fmaf(a, c.x, c.z));
        t = fmaf(SLOPE, fminf(t, 0.f), fmaxf(t, 0.f));      // leaky relu
        const float4* wrow = wpad4 + m * 32 + jq4;          // uniform
        float4 w0 = wrow[0], w1 = wrow[1];
        acc[0] = fmaf(t, w0.x, acc[0]);
        acc[1] = fmaf(t, w0.y, acc[1]);
        acc[2] = fmaf(t, w0.z, acc[2]);
        acc[3] = fmaf(t, w0.w, acc[3]);
        acc[4] = fmaf(t, w1.x, acc[4]);
        acc[5] = fmaf(t, w1.y, acc[5]);
        acc[6] = fmaf(t, w1.z, acc[6]);
        acc[7] = fmaf(t, w1.w, acc[7]);
    }

    // non-atomic: thread owns cols [8*wave, 8*wave+8) of its node's row
    const int col0 = wave * 8;
#pragma unroll
    for (int j = 0; j < 8; ++j)
        red[lane * RSTRIDE + col0 + j] = acc[j] + lb2p[col0 + j];  // pad cols: 0 + (-1e30)
    __syncthreads();

    // log_softmax: 16 threads per row, 8 cols each; reduce over width-16 shuffle groups
    int row = tid >> 4, sub = tid & 15;
    const float* rrow = &red[row * RSTRIDE + sub * 8];
    float mx = -1e30f;
#pragma unroll
    for (int j = 0; j < 8; ++j) mx = fmaxf(mx, rrow[j]);
    mx = fmaxf(mx, __shfl_xor(mx, 1, 16));
    mx = fmaxf(mx, __shfl_xor(mx, 2, 16));
    mx = fmaxf(mx, __shfl_xor(mx, 4, 16));
    mx = fmaxf(mx, __shfl_xor(mx, 8, 16));
    float sm = 0.f;
#pragma unroll
    for (int j = 0; j < 8; ++j) sm += expf(rrow[j] - mx);
    sm += __shfl_xor(sm, 1, 16);
    sm += __shfl_xor(sm, 2, 16);
    sm += __shfl_xor(sm, 4, 16);
    sm += __shfl_xor(sm, 8, 16);
    float lz = mx + logf(sm);
    int onode = blockIdx.x * 64 + row;
    if (onode < N_NODES) {
        int c0 = sub * 8;
        int jend = 124 - c0; if (jend > 8) jend = 8;
        for (int j = 0; j < jend; ++j) out[onode * 124 + c0 + j] = rrow[j] - lz;
    }
}

extern "C" void kernel_launch(void* const* d_in, const int* in_sizes, int n_in,
                              void* d_out, int out_size, void* d_ws, size_t ws_size,
                              hipStream_t stream) {
    const float* x     = (const float*)d_in[0];
    const int*   ei    = (const int*)d_in[1];
    const int*   src   = ei;
    const int*   dst   = ei + N_EDGES;
    const float* W1    = (const float*)d_in[2];
    const float* b1    = (const float*)d_in[3];
    const float* W2    = (const float*)d_in[4];
    const float* b2    = (const float*)d_in[5];
    const float* gamma = (const float*)d_in[6];
    const float* beta  = (const float*)d_in[7];
    const float* rmean = (const float*)d_in[8];
    const float* rvar  = (const float*)d_in[9];
    const float* lW1   = (const float*)d_in[10];
    const float* lb1   = (const float*)d_in[11];
    const float* lW2   = (const float*)d_in[12];
    const float* lb2   = (const float*)d_in[13];
    float* out = (float*)d_out;
    float* ws  = (float*)d_ws;

    int*   deg   = (int*)(ws + OFF_DEG);
    float* dinv  = ws + OFF_DINV;
    float* agg1  = ws + OFF_AGG1;
    float* agg2  = ws + OFF_AGG2;
    float* cnode = ws + OFF_CNODE;
    float* v     = ws + OFF_V;
    float* u     = ws + OFF_U;
    float* r     = ws + OFF_R;
    float* ru    = ws + OFF_RU;
    float* s     = ws + OFF_S;
    float* wpad  = ws + OFF_WPAD;
    float* lb2p  = ws + OFF_LB2P;
    float4* rrs  = (float4*)(ws + OFF_RRS);

    // single memset covers deg + all atomic-accumulation targets
    hipMemsetAsync(ws, 0, OFF_ZEND * sizeof(float), stream);

    K1_deg_v<<<256 + 625, 256, 0, stream>>>(dst, deg, W1, b1, W2, v, u);
    K2_prep<<<79, 256, 0, stream>>>(deg, x, dinv, agg1, cnode);
    K3_edges1<<<625, 256, 0, stream>>>(src, dst, dinv, x, agg1, cnode);
    K4_init_rs<<<79 + 32, 256, 0, stream>>>(dinv, agg1, agg2, v, u, gamma, beta,
                                            rmean, rvar, b2, lW1, lb1, r, ru, s);
    K5_edges2_pad<<<625 + 128, 256, 0, stream>>>(src, dst, dinv, agg1, agg2,
                                                 lW2, lb2, r, ru, s, wpad, lb2p, rrs);
    K6_final<<<(N_NODES + 63) / 64, 1024, 0, stream>>>(agg2, cnode, rrs,
                                                       (const float4*)wpad, lb2p, out);
}

// Round 4
// 158.281 us; speedup vs baseline: 1.2986x; 1.2986x over previous
//
#include <hip/hip_runtime.h>
#include <math.h>

#define N_NODES 20000
#define N_EDGES 160000
#define EPSB 1e-5f
#define SLOPE 0.01f

typedef __attribute__((ext_vector_type(8))) short short8;   // 8 bf16 (4 VGPRs)
typedef __attribute__((ext_vector_type(4))) float f32x4;    // MFMA C/D

// ---- workspace layout (float element offsets) ----
#define OFF_DEG    0        // int[20000]
#define OFF_DINV   20000    // float[20000]
#define OFF_AGG1   40000    // float[20000]
#define OFF_AGG2   60000    // float[20000]
#define OFF_CNODE  80000    // float[20000]
#define OFF_V      100000   // float[1024]
#define OFF_U      101024   // float[1024]
#define OFF_R      102048   // float[256]
#define OFF_RU     102304   // float[256]
#define OFF_S      102560   // float[256]
#define OFF_ZEND   102816   // end of zeroed region
#define OFF_BFRAG  102816   // bf16[8 ct][8 ks][64 lane][8 j] = 32768 halves = 16384 floats
#define OFF_RRS    119200   // float4[256] (119200*4 % 16 == 0)

__device__ __forceinline__ unsigned short f2bf(float f) {
    unsigned u = __float_as_uint(f);
    return (unsigned short)((u + 0x7FFFu + ((u >> 16) & 1u)) >> 16);   // RNE
}

// K1: blocks [0,256) compute v,u; blocks [256,881) degree atomics.
__global__ void K1_deg_v(const int* __restrict__ dst, int* __restrict__ deg,
                         const float* __restrict__ W1, const float* __restrict__ b1,
                         const float* __restrict__ W2,
                         float* __restrict__ v, float* __restrict__ u) {
    int b = blockIdx.x;
    if (b < 256) {
        int k  = (b & 3) * 256 + threadIdx.x;
        int c0 = (b >> 2) * 32;
        float av = 0.f, au = 0.f;
        for (int c = c0; c < c0 + 32; ++c) {
            float w = W2[c * 1024 + k];
            av = fmaf(W1[c], w, av);
            au = fmaf(b1[c], w, au);
        }
        atomicAdd(&v[k], av);
        atomicAdd(&u[k], au);
    } else {
        int e = (b - 256) * 256 + threadIdx.x;
        if (e < N_EDGES) atomicAdd(&deg[dst[e]], 1);
    }
}

// K2: dinv + self-loop init for agg1 and cnode
__global__ void K2_prep(const int* __restrict__ deg, const float* __restrict__ x,
                        float* __restrict__ dinv, float* __restrict__ agg1,
                        float* __restrict__ cnode) {
    int i = blockIdx.x * blockDim.x + threadIdx.x;
    if (i < N_NODES) {
        float di = rsqrtf((float)(deg[i] + 1));
        dinv[i] = di;
        float d2 = di * di;
        agg1[i]  = d2 * x[i];
        cnode[i] = d2;
    }
}

// K3: first edge aggregation (agg1, cnode)
__global__ void K3_edges1(const int* __restrict__ src, const int* __restrict__ dst,
                          const float* __restrict__ dinv, const float* __restrict__ x,
                          float* __restrict__ agg1, float* __restrict__ cnode) {
    int e = blockIdx.x * blockDim.x + threadIdx.x;
    if (e < N_EDGES) {
        int s = src[e], d = dst[e];
        float nrm = dinv[s] * dinv[d];
        atomicAdd(&agg1[d], nrm * x[s]);
        atomicAdd(&cnode[d], nrm);
    }
}

// K4: blocks [0,79) agg2 self-loop init; blocks [79,111) fold BN + Linear1 into r/ru/s.
__global__ void K4_init_rs(const float* __restrict__ dinv, const float* __restrict__ agg1,
                           float* __restrict__ agg2,
                           const float* __restrict__ v, const float* __restrict__ u,
                           const float* __restrict__ gamma, const float* __restrict__ beta,
                           const float* __restrict__ mean, const float* __restrict__ var,
                           const float* __restrict__ b2, const float* __restrict__ lW1,
                           const float* __restrict__ lb1,
                           float* __restrict__ r, float* __restrict__ ru, float* __restrict__ s) {
    int b = blockIdx.x;
    if (b < 79) {
        int i = b * 256 + threadIdx.x;
        if (i < N_NODES) agg2[i] = dinv[i] * dinv[i] * agg1[i];
    } else {
        int m  = threadIdx.x;
        int k0 = (b - 79) * 32;
        float ar = 0.f, aru = 0.f, as = 0.f;
        for (int k = k0; k < k0 + 32; ++k) {
            float g = gamma[k] * rsqrtf(var[k] + EPSB);
            float w = lW1[k * 256 + m];
            ar  = fmaf(v[k] * g, w, ar);
            aru = fmaf(u[k] * g, w, aru);
            as  = fmaf(fmaf(b2[k] - mean[k], g, beta[k]), w, as);
        }
        if (b == 79) as += lb1[m];
        atomicAdd(&r[m], ar);
        atomicAdd(&ru[m], aru);
        atomicAdd(&s[m], as);
    }
}

// K5: blocks [0,625) second edge aggregation; blocks [625,641) build bf16 B-fragments
// of lW2 in MFMA B-operand order (B[k][n]: n=lane&15, k=ks*32+(lane>>4)*8+j);
// block 641 packs rrs.
__global__ void K5_edges2_pad(const int* __restrict__ src, const int* __restrict__ dst,
                              const float* __restrict__ dinv, const float* __restrict__ agg1,
                              float* __restrict__ agg2,
                              const float* __restrict__ lW2,
                              const float* __restrict__ r, const float* __restrict__ ru,
                              const float* __restrict__ s,
                              unsigned short* __restrict__ bfrag, float4* __restrict__ rrs) {
    int b = blockIdx.x;
    if (b < 625) {
        int e = b * 256 + threadIdx.x;
        if (e < N_EDGES) {
            int sn = src[e], d = dst[e];
            atomicAdd(&agg2[d], dinv[sn] * dinv[d] * agg1[sn]);
        }
    } else if (b < 641) {
        int i = (b - 625) * 256 + threadIdx.x;   // 0..4095 = (ct,ks,lane)
        int ct = i >> 9, ks = (i >> 6) & 7, lane = i & 63;
        int n = ct * 16 + (lane & 15);
        int kb = ks * 32 + (lane >> 4) * 8;
        union { unsigned short u[8]; short8 v; } pk;
#pragma unroll
        for (int j = 0; j < 8; ++j)
            pk.u[j] = (n < 124) ? f2bf(lW2[(kb + j) * 124 + n]) : (unsigned short)0;
        ((short8*)bfrag)[i] = pk.v;
    } else {
        int i = threadIdx.x;
        rrs[i] = make_float4(r[i], ru[i], s[i], 0.f);
    }
}

// K6: MFMA final stage. Block = 256 thr (4 waves); grid-strides over 2 node-tiles
// of 16 nodes. Phase A: T[16 node][256 m] = leaky(a*r+cn*ru+s) as bf16 in LDS
// (thread = m, loop nodes; rrs read once/m, coalesced). Phase B: wave w owns
// cols [32w,32w+32): 8 A-frags (ds_read_b128) x 2 B-col-tiles preloaded in
// 64 VGPRs -> 16 mfma_f32_16x16x32_bf16. Epilogue: logits tile in LDS, fused
// log_softmax (16 thr/node), +lb2.
#define T_STRIDE 264   // halves; 528 B rows keep 16B alignment for ds_read_b128
__global__ __launch_bounds__(256, 2) void K6_final(
    const float* __restrict__ agg2, const float* __restrict__ cnode,
    const float4* __restrict__ rrs, const short8* __restrict__ bfrag,
    const float* __restrict__ lb2, float* __restrict__ out) {
    __shared__ unsigned short tsh[16 * T_STRIDE];   // 8448 B
    __shared__ float a_sh[16], cn_sh[16];
    __shared__ float logits[16 * 132];              // 8448 B
    int tid  = threadIdx.x;
    int lane = tid & 63;
    int wave = __builtin_amdgcn_readfirstlane(tid >> 6);   // 0..3
    int row  = lane & 15, quad = lane >> 4;

    // preload B-fragments for this wave's two 16-col tiles (reused across node-tiles)
    short8 bf0[8], bf1[8];
#pragma unroll
    for (int ks = 0; ks < 8; ++ks) {
        bf0[ks] = bfrag[((wave * 2 + 0) * 8 + ks) * 64 + lane];
        bf1[ks] = bfrag[((wave * 2 + 1) * 8 + ks) * 64 + lane];
    }

    for (int it = 0; it < 2; ++it) {
        int node0 = (blockIdx.x * 2 + it) * 16;    // 1250 tiles = 625 blocks x 2, exact
        if (tid < 16)      a_sh[tid]       = agg2[node0 + tid];
        else if (tid < 32) cn_sh[tid - 16] = cnode[node0 + tid - 16];
        float4 c = rrs[tid];                        // m = tid, coalesced, once per m
        __syncthreads();                            // (0) a_sh ready; prev readers of tsh done

        // Phase A: T tile, bf16
#pragma unroll
        for (int n = 0; n < 16; ++n) {
            float t = fmaf(cn_sh[n], c.y, fmaf(a_sh[n], c.x, c.z));
            t = fmaf(SLOPE, fminf(t, 0.f), fmaxf(t, 0.f));
            tsh[n * T_STRIDE + tid] = f2bf(t);
        }
        __syncthreads();                            // (1)

        // Phase B: MFMA
        f32x4 acc0 = {0.f, 0.f, 0.f, 0.f}, acc1 = {0.f, 0.f, 0.f, 0.f};
        const unsigned short* tb = &tsh[row * T_STRIDE + quad * 8];
#pragma unroll
        for (int ks = 0; ks < 8; ++ks) {
            short8 af = *(const short8*)(tb + ks * 32);   // ds_read_b128, 16B aligned
            acc0 = __builtin_amdgcn_mfma_f32_16x16x32_bf16(af, bf0[ks], acc0, 0, 0, 0);
            acc1 = __builtin_amdgcn_mfma_f32_16x16x32_bf16(af, bf1[ks], acc1, 0, 0, 0);
        }
        // D layout: D[node=(lane>>4)*4+reg][col=lane&15]
        int colbase = wave * 32;
#pragma unroll
        for (int rg = 0; rg < 4; ++rg) {
            int rw = quad * 4 + rg;
            logits[rw * 132 + colbase + row]      = acc0[rg];
            logits[rw * 132 + colbase + 16 + row] = acc1[rg];
        }
        __syncthreads();                            // (2)

        // log_softmax: 16 threads per node, 8 cols each (last sub: 4 valid)
        int nd = tid >> 4, sub = tid & 15, c0 = sub * 8;
        int jend = 124 - c0; if (jend > 8) jend = 8;
        float vbuf[8];
        const float* lrow = &logits[nd * 132 + c0];
        float mx = -1e30f;
        for (int j = 0; j < jend; ++j) {
            vbuf[j] = lrow[j] + lb2[c0 + j];
            mx = fmaxf(mx, vbuf[j]);
        }
        mx = fmaxf(mx, __shfl_xor(mx, 1, 16));
        mx = fmaxf(mx, __shfl_xor(mx, 2, 16));
        mx = fmaxf(mx, __shfl_xor(mx, 4, 16));
        mx = fmaxf(mx, __shfl_xor(mx, 8, 16));
        float sm = 0.f;
        for (int j = 0; j < jend; ++j) sm += __expf(vbuf[j] - mx);
        sm += __shfl_xor(sm, 1, 16);
        sm += __shfl_xor(sm, 2, 16);
        sm += __shfl_xor(sm, 4, 16);
        sm += __shfl_xor(sm, 8, 16);
        float lz = mx + __logf(sm);
        float* orow = out + (node0 + nd) * 124 + c0;
        for (int j = 0; j < jend; ++j) orow[j] = vbuf[j] - lz;
    }
}

extern "C" void kernel_launch(void* const* d_in, const int* in_sizes, int n_in,
                              void* d_out, int out_size, void* d_ws, size_t ws_size,
                              hipStream_t stream) {
    const float* x     = (const float*)d_in[0];
    const int*   ei    = (const int*)d_in[1];
    const int*   src   = ei;
    const int*   dst   = ei + N_EDGES;
    const float* W1    = (const float*)d_in[2];
    const float* b1    = (const float*)d_in[3];
    const float* W2    = (const float*)d_in[4];
    const float* b2    = (const float*)d_in[5];
    const float* gamma = (const float*)d_in[6];
    const float* beta  = (const float*)d_in[7];
    const float* rmean = (const float*)d_in[8];
    const float* rvar  = (const float*)d_in[9];
    const float* lW1   = (const float*)d_in[10];
    const float* lb1   = (const float*)d_in[11];
    const float* lW2   = (const float*)d_in[12];
    const float* lb2   = (const float*)d_in[13];
    float* out = (float*)d_out;
    float* ws  = (float*)d_ws;

    int*   deg   = (int*)(ws + OFF_DEG);
    float* dinv  = ws + OFF_DINV;
    float* agg1  = ws + OFF_AGG1;
    float* agg2  = ws + OFF_AGG2;
    float* cnode = ws + OFF_CNODE;
    float* v     = ws + OFF_V;
    float* u     = ws + OFF_U;
    float* r     = ws + OFF_R;
    float* ru    = ws + OFF_RU;
    float* s     = ws + OFF_S;
    unsigned short* bfrag = (unsigned short*)(ws + OFF_BFRAG);
    float4* rrs  = (float4*)(ws + OFF_RRS);

    hipMemsetAsync(ws, 0, OFF_ZEND * sizeof(float), stream);

    K1_deg_v<<<256 + 625, 256, 0, stream>>>(dst, deg, W1, b1, W2, v, u);
    K2_prep<<<79, 256, 0, stream>>>(deg, x, dinv, agg1, cnode);
    K3_edges1<<<625, 256, 0, stream>>>(src, dst, dinv, x, agg1, cnode);
    K4_init_rs<<<79 + 32, 256, 0, stream>>>(dinv, agg1, agg2, v, u, gamma, beta,
                                            rmean, rvar, b2, lW1, lb1, r, ru, s);
    K5_edges2_pad<<<625 + 16 + 1, 256, 0, stream>>>(src, dst, dinv, agg1, agg2,
                                                    lW2, r, ru, s, bfrag, rrs);
    K6_final<<<625, 256, 0, stream>>>(agg2, cnode, rrs, (const short8*)bfrag, lb2, out);
}